// Round 1
// baseline (534.972 us; speedup 1.0000x reference)
//
#include <hip/hip_runtime.h>
#include <hip/hip_bf16.h>
#include <cstdint>

// GraphSAGEMean: x = relu chain of 4 linears over N rows; agg = row-mean of E.
// Fused single-pass kernel: E -> LDS (bf16) -> 4 MFMA layers in-block -> out.
// Weights pre-transposed to [out][in] bf16 in d_ws by prep_kernel.
//
// R1 change: ROWS 128 -> 64 (LDS 67.6KB -> 33.8KB) => 4 blocks/CU instead of 2
// (__launch_bounds__(256,4)). Theory: kernel was latency/phase-bound (MfmaUtil
// 12%, HBM 11%, occupancy 19.7%); doubling resident blocks lets load/compute/
// store phases of independent blocks overlap on each CU.

#define N_ROWS 200000
#define O_DIM  128
#define ROWS   64         // rows per block; 3125 * 64 == 200000 exactly (no tail)
#define PITCH  264        // 256 + 8 bf16 pad: B-frag reads land 2-way on banks (free)

typedef short bf16x8 __attribute__((ext_vector_type(8)));   // 8 bf16 = 4 VGPRs
typedef float f32x4  __attribute__((ext_vector_type(4)));

__device__ __forceinline__ unsigned short rne_bf16(float f) {
  unsigned int u = __float_as_uint(f);
  u += 0x7FFFu + ((u >> 16) & 1u);      // round-to-nearest-even
  return (unsigned short)(u >> 16);
}

// Transpose + bf16-cast all weights into ws: Wt[o][i] = bf16(W[i][o]).
// Layout in ws (ushort elems): Wt1 @0, Wt2 @65536, Wt3 @131072, Wto @196608.
__global__ __launch_bounds__(256) void prep_kernel(
    const float* __restrict__ W1, const float* __restrict__ W2,
    const float* __restrict__ W3, const float* __restrict__ Wo,
    unsigned short* __restrict__ wt) {
  const int b = blockIdx.x;
  const int t = threadIdx.x;
  if (b < 256) {
    wt[b * 256 + t] = rne_bf16(W1[t * 256 + b]);
  } else if (b < 512) {
    const int o = b - 256;
    wt[65536 + o * 256 + t] = rne_bf16(W2[t * 256 + o]);
  } else if (b < 768) {
    const int o = b - 512;
    wt[131072 + o * 256 + t] = rne_bf16(W3[t * 256 + o]);
  } else {
    const int o = b - 768;
    wt[196608 + o * 256 + t] = rne_bf16(Wo[t * 128 + o]);
  }
}

// One layer, operand-swapped: D[m=out_ch][n=row] = sum_k Wt[m][k] * act[n][k].
// A-frag (Wt) from global (L2-hot), B-frag (act) from LDS, C written back to
// act as bf16 (4 consecutive channels per lane -> 8B ds_write).
// NB = 4 row-blocks of 16 (64 rows/block).
template <int MB, bool RELU, bool LAST>
__device__ __forceinline__ void do_layer(
    const unsigned short* __restrict__ wt, const float* __restrict__ bias,
    float* __restrict__ out_x, long row0, unsigned short* act,
    int wave, int lane) {
  const int lc   = lane & 15;
  const int quad = lane >> 4;
  const int m_base = wave * (MB * 16);   // 64 ch/wave (layers 1-3), 32 (layer 4)

  f32x4 acc[MB][4];
#pragma unroll
  for (int mb = 0; mb < MB; ++mb)
#pragma unroll
    for (int nb = 0; nb < 4; ++nb)
      acc[mb][nb] = (f32x4){0.f, 0.f, 0.f, 0.f};

#pragma unroll
  for (int k0 = 0; k0 < 256; k0 += 32) {
    bf16x8 bfr[4];
#pragma unroll
    for (int nb = 0; nb < 4; ++nb)
      bfr[nb] = *(const bf16x8*)&act[(nb * 16 + lc) * PITCH + k0 + 8 * quad];
#pragma unroll
    for (int mb = 0; mb < MB; ++mb) {
      bf16x8 afr = *(const bf16x8*)&wt[(m_base + mb * 16 + lc) * 256 + k0 + 8 * quad];
#pragma unroll
      for (int nb = 0; nb < 4; ++nb)
        acc[mb][nb] = __builtin_amdgcn_mfma_f32_16x16x32_bf16(afr, bfr[nb],
                                                              acc[mb][nb], 0, 0, 0);
    }
  }
  __syncthreads();   // all B-frag reads of act done before overwrite

#pragma unroll
  for (int mb = 0; mb < MB; ++mb) {
    const int ch = m_base + mb * 16 + 4 * quad;
    f32x4 bb = *(const f32x4*)(bias + ch);
#pragma unroll
    for (int nb = 0; nb < 4; ++nb) {
      f32x4 v = acc[mb][nb] + bb;
      if (RELU) {
#pragma unroll
        for (int j = 0; j < 4; ++j) v[j] = fmaxf(v[j], 0.f);
      }
      const int r = nb * 16 + lc;
      if (!LAST) {
        ushort4 h;
        h.x = rne_bf16(v[0]); h.y = rne_bf16(v[1]);
        h.z = rne_bf16(v[2]); h.w = rne_bf16(v[3]);
        *(ushort4*)&act[r * PITCH + ch] = h;          // 8B LDS write
      } else {
        const long gr = row0 + r;
        *(f32x4*)&out_x[gr * O_DIM + ch] = v;         // 16B store, no tail (3125*64==N)
      }
    }
  }
  __syncthreads();   // writes visible before next layer's reads
}

__global__ __launch_bounds__(256, 4) void sage_kernel(
    const float* __restrict__ E,
    const float* __restrict__ b1, const float* __restrict__ b2,
    const float* __restrict__ b3, const float* __restrict__ bo,
    const unsigned short* __restrict__ wts,
    float* __restrict__ out_x, float* __restrict__ out_agg) {
  __shared__ __align__(16) unsigned short act[ROWS * PITCH];  // 33792 B -> 4 blocks/CU

  const int t    = threadIdx.x;
  const int wave = t >> 6;
  const int lane = t & 63;
  const long row0 = (long)blockIdx.x * ROWS;

  // Load E tile -> bf16 LDS; fused row-mean (output 1). 16 rows per wave.
#pragma unroll 8
  for (int i = 0; i < 16; ++i) {
    const int r = 4 * i + wave;          // wave g handles rows == g (mod 4)
    const long gr = row0 + r;
    f32x4 v = *(const f32x4*)(E + gr * 256 + lane * 4);
    ushort4 h;
    h.x = rne_bf16(v[0]); h.y = rne_bf16(v[1]);
    h.z = rne_bf16(v[2]); h.w = rne_bf16(v[3]);
    *(ushort4*)&act[r * PITCH + lane * 4] = h;
    float s = v[0] + v[1] + v[2] + v[3];
    s += __shfl_down(s, 32);
    s += __shfl_down(s, 16);
    s += __shfl_down(s, 8);
    s += __shfl_down(s, 4);
    s += __shfl_down(s, 2);
    s += __shfl_down(s, 1);
    if (lane == 0) out_agg[gr] = s * (1.0f / 256.0f);
  }
  __syncthreads();

  do_layer<4, true,  false>(wts,          b1, nullptr, row0, act, wave, lane);
  do_layer<4, true,  false>(wts + 65536,  b2, nullptr, row0, act, wave, lane);
  do_layer<4, true,  false>(wts + 131072, b3, nullptr, row0, act, wave, lane);
  do_layer<2, false, true >(wts + 196608, bo, out_x,   row0, act, wave, lane);
}

extern "C" void kernel_launch(void* const* d_in, const int* in_sizes, int n_in,
                              void* d_out, int out_size, void* d_ws, size_t ws_size,
                              hipStream_t stream) {
  const float* E  = (const float*)d_in[0];
  // d_in[1] = adj_keys: mathematically unused (identity gather in reference)
  const float* W1 = (const float*)d_in[2];
  const float* b1 = (const float*)d_in[3];
  const float* W2 = (const float*)d_in[4];
  const float* b2 = (const float*)d_in[5];
  const float* W3 = (const float*)d_in[6];
  const float* b3 = (const float*)d_in[7];
  const float* Wo = (const float*)d_in[8];
  const float* bo = (const float*)d_in[9];

  float* out_x   = (float*)d_out;
  float* out_agg = out_x + (size_t)N_ROWS * O_DIM;
  unsigned short* wts = (unsigned short*)d_ws;   // 458752 B used

  prep_kernel<<<896, 256, 0, stream>>>(W1, W2, W3, Wo, wts);

  const int grid = N_ROWS / ROWS;                // 3125, exact
  sage_kernel<<<grid, 256, 0, stream>>>(E, b1, b2, b3, bo, wts, out_x, out_agg);
}

// Round 2
// 513.363 us; speedup vs baseline: 1.0421x; 1.0421x over previous
//
#include <hip/hip_runtime.h>
#include <hip/hip_bf16.h>
#include <cstdint>

// GraphSAGEMean: x = relu chain of 4 linears over N rows; agg = row-mean of E.
// Fused single-pass kernel: E -> LDS (bf16) -> 4 MFMA layers in-block -> out.
// Weights pre-transposed to [out][in] bf16 in d_ws by prep_kernel.
//
// R1: ROWS 128->64, 4 blocks/CU. Occupancy 19.7->40.5% but dur unchanged ->
//     NOT occupancy-bound.
// R2 theory: hbm_bytes/hbm_gbps == dur (315us) -> kernel is HBM-transfer-bound
//     at 14% of peak = Little's-law MLP limit (~1.7KB in flight/CU). The E-load
//     loop interleaves each 16B load with ~50cyc of VALU (bf16 cvt + 6-shuffle
//     reduce), throttling issue to ~1 load/112cyc/wave. Fix: batch-issue all 16
//     row-loads per wave into registers (f32x4 v[16], +64 VGPR) BEFORE any
//     processing -> 4KB/wave in flight.

#define N_ROWS 200000
#define O_DIM  128
#define ROWS   64         // rows per block; 3125 * 64 == 200000 exactly (no tail)
#define PITCH  264        // 256 + 8 bf16 pad: B-frag reads land 2-way on banks (free)

typedef short bf16x8 __attribute__((ext_vector_type(8)));   // 8 bf16 = 4 VGPRs
typedef float f32x4  __attribute__((ext_vector_type(4)));

__device__ __forceinline__ unsigned short rne_bf16(float f) {
  unsigned int u = __float_as_uint(f);
  u += 0x7FFFu + ((u >> 16) & 1u);      // round-to-nearest-even
  return (unsigned short)(u >> 16);
}

// Transpose + bf16-cast all weights into ws: Wt[o][i] = bf16(W[i][o]).
// Layout in ws (ushort elems): Wt1 @0, Wt2 @65536, Wt3 @131072, Wto @196608.
__global__ __launch_bounds__(256) void prep_kernel(
    const float* __restrict__ W1, const float* __restrict__ W2,
    const float* __restrict__ W3, const float* __restrict__ Wo,
    unsigned short* __restrict__ wt) {
  const int b = blockIdx.x;
  const int t = threadIdx.x;
  if (b < 256) {
    wt[b * 256 + t] = rne_bf16(W1[t * 256 + b]);
  } else if (b < 512) {
    const int o = b - 256;
    wt[65536 + o * 256 + t] = rne_bf16(W2[t * 256 + o]);
  } else if (b < 768) {
    const int o = b - 512;
    wt[131072 + o * 256 + t] = rne_bf16(W3[t * 256 + o]);
  } else {
    const int o = b - 768;
    wt[196608 + o * 256 + t] = rne_bf16(Wo[t * 128 + o]);
  }
}

// One layer, operand-swapped: D[m=out_ch][n=row] = sum_k Wt[m][k] * act[n][k].
// A-frag (Wt) from global (L2-hot), B-frag (act) from LDS, C written back to
// act as bf16 (4 consecutive channels per lane -> 8B ds_write).
// NB = 4 row-blocks of 16 (64 rows/block).
template <int MB, bool RELU, bool LAST>
__device__ __forceinline__ void do_layer(
    const unsigned short* __restrict__ wt, const float* __restrict__ bias,
    float* __restrict__ out_x, long row0, unsigned short* act,
    int wave, int lane) {
  const int lc   = lane & 15;
  const int quad = lane >> 4;
  const int m_base = wave * (MB * 16);   // 64 ch/wave (layers 1-3), 32 (layer 4)

  f32x4 acc[MB][4];
#pragma unroll
  for (int mb = 0; mb < MB; ++mb)
#pragma unroll
    for (int nb = 0; nb < 4; ++nb)
      acc[mb][nb] = (f32x4){0.f, 0.f, 0.f, 0.f};

#pragma unroll
  for (int k0 = 0; k0 < 256; k0 += 32) {
    bf16x8 bfr[4];
#pragma unroll
    for (int nb = 0; nb < 4; ++nb)
      bfr[nb] = *(const bf16x8*)&act[(nb * 16 + lc) * PITCH + k0 + 8 * quad];
#pragma unroll
    for (int mb = 0; mb < MB; ++mb) {
      bf16x8 afr = *(const bf16x8*)&wt[(m_base + mb * 16 + lc) * 256 + k0 + 8 * quad];
#pragma unroll
      for (int nb = 0; nb < 4; ++nb)
        acc[mb][nb] = __builtin_amdgcn_mfma_f32_16x16x32_bf16(afr, bfr[nb],
                                                              acc[mb][nb], 0, 0, 0);
    }
  }
  __syncthreads();   // all B-frag reads of act done before overwrite

#pragma unroll
  for (int mb = 0; mb < MB; ++mb) {
    const int ch = m_base + mb * 16 + 4 * quad;
    f32x4 bb = *(const f32x4*)(bias + ch);
#pragma unroll
    for (int nb = 0; nb < 4; ++nb) {
      f32x4 v = acc[mb][nb] + bb;
      if (RELU) {
#pragma unroll
        for (int j = 0; j < 4; ++j) v[j] = fmaxf(v[j], 0.f);
      }
      const int r = nb * 16 + lc;
      if (!LAST) {
        ushort4 h;
        h.x = rne_bf16(v[0]); h.y = rne_bf16(v[1]);
        h.z = rne_bf16(v[2]); h.w = rne_bf16(v[3]);
        *(ushort4*)&act[r * PITCH + ch] = h;          // 8B LDS write
      } else {
        const long gr = row0 + r;
        *(f32x4*)&out_x[gr * O_DIM + ch] = v;         // 16B store, no tail (3125*64==N)
      }
    }
  }
  __syncthreads();   // writes visible before next layer's reads
}

__global__ __launch_bounds__(256, 4) void sage_kernel(
    const float* __restrict__ E,
    const float* __restrict__ b1, const float* __restrict__ b2,
    const float* __restrict__ b3, const float* __restrict__ bo,
    const unsigned short* __restrict__ wts,
    float* __restrict__ out_x, float* __restrict__ out_agg) {
  __shared__ __align__(16) unsigned short act[ROWS * PITCH];  // 33792 B -> 4 blocks/CU

  const int t    = threadIdx.x;
  const int wave = t >> 6;
  const int lane = t & 63;
  const long row0 = (long)blockIdx.x * ROWS;

  // Phase A: batch-issue ALL 16 row-loads for this wave (4KB in flight/wave).
  // No VALU between loads -> global_load_dwordx4 back-to-back, vmcnt drains
  // incrementally in phase B.
  f32x4 v[16];
#pragma unroll
  for (int i = 0; i < 16; ++i) {
    const int r = 4 * i + wave;          // wave g handles rows == g (mod 4)
    v[i] = *(const f32x4*)(E + (row0 + r) * 256 + lane * 4);
  }

  // Phase B: convert -> bf16 LDS tile; fused row-mean (output 1).
#pragma unroll
  for (int i = 0; i < 16; ++i) {
    const int r = 4 * i + wave;
    const long gr = row0 + r;
    ushort4 h;
    h.x = rne_bf16(v[i][0]); h.y = rne_bf16(v[i][1]);
    h.z = rne_bf16(v[i][2]); h.w = rne_bf16(v[i][3]);
    *(ushort4*)&act[r * PITCH + lane * 4] = h;
    float s = v[i][0] + v[i][1] + v[i][2] + v[i][3];
    s += __shfl_down(s, 32);
    s += __shfl_down(s, 16);
    s += __shfl_down(s, 8);
    s += __shfl_down(s, 4);
    s += __shfl_down(s, 2);
    s += __shfl_down(s, 1);
    if (lane == 0) out_agg[gr] = s * (1.0f / 256.0f);
  }
  __syncthreads();

  do_layer<4, true,  false>(wts,          b1, nullptr, row0, act, wave, lane);
  do_layer<4, true,  false>(wts + 65536,  b2, nullptr, row0, act, wave, lane);
  do_layer<4, true,  false>(wts + 131072, b3, nullptr, row0, act, wave, lane);
  do_layer<2, false, true >(wts + 196608, bo, out_x,   row0, act, wave, lane);
}

extern "C" void kernel_launch(void* const* d_in, const int* in_sizes, int n_in,
                              void* d_out, int out_size, void* d_ws, size_t ws_size,
                              hipStream_t stream) {
  const float* E  = (const float*)d_in[0];
  // d_in[1] = adj_keys: mathematically unused (identity gather in reference)
  const float* W1 = (const float*)d_in[2];
  const float* b1 = (const float*)d_in[3];
  const float* W2 = (const float*)d_in[4];
  const float* b2 = (const float*)d_in[5];
  const float* W3 = (const float*)d_in[6];
  const float* b3 = (const float*)d_in[7];
  const float* Wo = (const float*)d_in[8];
  const float* bo = (const float*)d_in[9];

  float* out_x   = (float*)d_out;
  float* out_agg = out_x + (size_t)N_ROWS * O_DIM;
  unsigned short* wts = (unsigned short*)d_ws;   // 458752 B used

  prep_kernel<<<896, 256, 0, stream>>>(W1, W2, W3, Wo, wts);

  const int grid = N_ROWS / ROWS;                // 3125, exact
  sage_kernel<<<grid, 256, 0, stream>>>(E, b1, b2, b3, bo, wts, out_x, out_agg);
}